// Round 1
// baseline (805.880 us; speedup 1.0000x reference)
//
#include <hip/hip_runtime.h>

typedef _Float16 half8 __attribute__((ext_vector_type(8)));
typedef float floatx16 __attribute__((ext_vector_type(16)));

#define B_   128
#define H_   4
#define SEQ_ 256
#define E_   64
#define D_   64
#define LH_  64
#define IN_  (LH_*E_)    // 4096
#define OUT_ (LH_*D_)    // 4096
#define QKV_MAT_ELEMS (B_*H_*OUT_)  // 2097152 halfs per matrix

// ---------------------------------------------------------------------------
// Kernel 1: fused QKV projection.  C[b, o] = sum_i X[b,i] * W[o,i] + bias[o]
// per (mat in {Q,K,V}, head h).  fp32 inputs, f16 MFMA, fp32 accum,
// f16 output into workspace laid out [mat][b][h][o].
// Block: 256 thr, tile 128(M=batch) x 64(N=o), BK=64. 768 blocks = 3/CU.
// LDS staged via XOR-swizzled 16B units -> conflict-free ds_read_b128.
// ---------------------------------------------------------------------------
__global__ __launch_bounds__(256, 3) void qkv_gemm(
    const float* __restrict__ seq,
    const float* __restrict__ WQ, const float* __restrict__ bQ,
    const float* __restrict__ WK, const float* __restrict__ bK,
    const float* __restrict__ WV, const float* __restrict__ bV,
    _Float16* __restrict__ qkv)
{
    const int o0  = blockIdx.x * 64;
    const int h   = blockIdx.y;
    const int mat = blockIdx.z;
    const float* __restrict__ W    = (mat == 0) ? WQ : (mat == 1) ? WK : WV;
    const float* __restrict__ bias = (mat == 0) ? bQ : (mat == 1) ? bK : bV;

    // 16B units: unit (row, k8) stored at row*8 + (k8 ^ (row&7))
    __shared__ half8 Xs[128 * 8];   // 16 KB
    __shared__ half8 Wt[64 * 8];    //  8 KB

    const int t    = threadIdx.x;
    const int wave = t >> 6;
    const int lane = t & 63;
    const int lrow = lane & 31;
    const int kg   = lane >> 5;

    floatx16 acc0, acc1;
    #pragma unroll
    for (int i = 0; i < 16; ++i) { acc0[i] = 0.f; acc1[i] = 0.f; }

    const size_t wbase = (size_t)h * IN_ * OUT_;

    for (int kt = 0; kt < 64; ++kt) {
        const int k0 = kt * 64;
        // stage X tile: 128 rows x 64 k (fp32 -> f16)
        #pragma unroll
        for (int i = 0; i < 4; ++i) {
            int lin = t + 256 * i;
            int r = lin >> 3, k8 = lin & 7;
            const float* src = seq + (size_t)r * (SEQ_*E_) + (size_t)h * IN_ + k0 + k8 * 8;
            float4 f0 = ((const float4*)src)[0];
            float4 f1 = ((const float4*)src)[1];
            half8 v;
            v[0] = (_Float16)f0.x; v[1] = (_Float16)f0.y;
            v[2] = (_Float16)f0.z; v[3] = (_Float16)f0.w;
            v[4] = (_Float16)f1.x; v[5] = (_Float16)f1.y;
            v[6] = (_Float16)f1.z; v[7] = (_Float16)f1.w;
            Xs[r * 8 + (k8 ^ (r & 7))] = v;
        }
        // stage W tile: 64 rows (o) x 64 k
        #pragma unroll
        for (int i = 0; i < 2; ++i) {
            int lin = t + 256 * i;
            int r = lin >> 3, k8 = lin & 7;
            const float* src = W + wbase + (size_t)(o0 + r) * IN_ + k0 + k8 * 8;
            float4 f0 = ((const float4*)src)[0];
            float4 f1 = ((const float4*)src)[1];
            half8 v;
            v[0] = (_Float16)f0.x; v[1] = (_Float16)f0.y;
            v[2] = (_Float16)f0.z; v[3] = (_Float16)f0.w;
            v[4] = (_Float16)f1.x; v[5] = (_Float16)f1.y;
            v[6] = (_Float16)f1.z; v[7] = (_Float16)f1.w;
            Wt[r * 8 + (k8 ^ (r & 7))] = v;
        }
        __syncthreads();

        const int arow = wave * 32 + lrow;
        #pragma unroll
        for (int s = 0; s < 4; ++s) {
            int k8i = s * 2 + kg;   // A/B fragment: lane holds 8 contiguous k at kg*8
            half8 a  = Xs[arow * 8 + (k8i ^ (arow & 7))];
            half8 b0 = Wt[lrow * 8 + (k8i ^ (lrow & 7))];
            half8 b1 = Wt[(lrow + 32) * 8 + (k8i ^ (lrow & 7))];
            acc0 = __builtin_amdgcn_mfma_f32_32x32x16_f16(a, b0, acc0, 0, 0, 0);
            acc1 = __builtin_amdgcn_mfma_f32_32x32x16_f16(a, b1, acc1, 0, 0, 0);
        }
        __syncthreads();
    }

    // epilogue: C/D layout col = lane&31, row = (reg&3) + 8*(reg>>2) + 4*(lane>>5)
    const float bv0 = bias[(size_t)h * OUT_ + o0 + lrow];
    const float bv1 = bias[(size_t)h * OUT_ + o0 + 32 + lrow];
    _Float16* dst = qkv + (size_t)mat * QKV_MAT_ELEMS;
    #pragma unroll
    for (int r = 0; r < 16; ++r) {
        int row = (r & 3) + 8 * (r >> 2) + 4 * kg;
        int b   = wave * 32 + row;
        size_t idx = ((size_t)(b * H_ + h)) * OUT_ + o0;
        dst[idx + lrow]      = (_Float16)(acc0[r] + bv0);
        dst[idx + 32 + lrow] = (_Float16)(acc1[r] + bv1);
    }
}

// ---------------------------------------------------------------------------
// Kernel 2: per-(b,h) local attention, fp32 math in LDS.
// scores[q,k] = Q[q]·K[k]; mask k>q -> -1e20; softmax over q (column-wise,
// faithful to reference's axis=2 softmax); Z = attn·V * 0.125.
// ---------------------------------------------------------------------------
__global__ __launch_bounds__(256, 2) void local_attn(
    const _Float16* __restrict__ qkv, float* __restrict__ out)
{
    __shared__ float Qs[64 * 65];
    __shared__ float Ks[64 * 65];
    __shared__ float Vs[64 * 65];
    __shared__ float Ss[64 * 65];

    const int t = threadIdx.x;
    const int h = blockIdx.x;
    const int b = blockIdx.y;
    const size_t base = ((size_t)(b * H_ + h)) * OUT_;

    #pragma unroll
    for (int i = 0; i < 2; ++i) {
        int unit = t + 256 * i;            // 512 units of 8 halfs per matrix
        int q = unit >> 3, d8 = unit & 7;
        half8 vq = *(const half8*)(qkv + base + q * 64 + d8 * 8);
        half8 vk = *(const half8*)(qkv + (size_t)QKV_MAT_ELEMS + base + q * 64 + d8 * 8);
        half8 vv = *(const half8*)(qkv + (size_t)2 * QKV_MAT_ELEMS + base + q * 64 + d8 * 8);
        #pragma unroll
        for (int j = 0; j < 8; ++j) {
            Qs[q * 65 + d8 * 8 + j] = (float)vq[j];
            Ks[q * 65 + d8 * 8 + j] = (float)vk[j];
            Vs[q * 65 + d8 * 8 + j] = (float)vv[j];
        }
    }
    __syncthreads();

    const int w = t >> 6, lane = t & 63;

    // scores: wave w owns q in [w*16, w*16+16); lane = k.
    // K row hoisted to regs; Q reads are wave-uniform (LDS broadcast).
    {
        float kr[64];
        #pragma unroll
        for (int d = 0; d < 64; ++d) kr[d] = Ks[lane * 65 + d];
        #pragma unroll 2
        for (int qi = 0; qi < 16; ++qi) {
            int q = w * 16 + qi;
            float s = 0.f;
            #pragma unroll
            for (int d = 0; d < 64; ++d) s += Qs[q * 65 + d] * kr[d];
            if (lane > q) s = -1e20f;      // triu(diagonal=1) mask
            Ss[q * 65 + lane] = s;
        }
    }
    __syncthreads();

    // softmax over q for each column k (threads 0..63)
    if (t < 64) {
        const int k = t;
        float m = -3.4e38f;
        for (int q = 0; q < 64; ++q) m = fmaxf(m, Ss[q * 65 + k]);
        float sum = 0.f;
        for (int q = 0; q < 64; ++q) {
            float e = __expf(Ss[q * 65 + k] - m);
            Ss[q * 65 + k] = e;
            sum += e;
        }
        float inv = 1.f / sum;
        for (int q = 0; q < 64; ++q) Ss[q * 65 + k] *= inv;
    }
    __syncthreads();

    // Z = attn @ V * 0.125: wave w owns q-range; lane = d. V column hoisted.
    {
        float vr[64];
        #pragma unroll
        for (int k = 0; k < 64; ++k) vr[k] = Vs[k * 65 + lane];
        #pragma unroll 2
        for (int qi = 0; qi < 16; ++qi) {
            int q = w * 16 + qi;
            float z = 0.f;
            #pragma unroll
            for (int k = 0; k < 64; ++k) z += Ss[q * 65 + k] * vr[k];
            out[((size_t)b * SEQ_ + h * LH_ + q) * D_ + lane] = z * 0.125f;
        }
    }
}

extern "C" void kernel_launch(void* const* d_in, const int* in_sizes, int n_in,
                              void* d_out, int out_size, void* d_ws, size_t ws_size,
                              hipStream_t stream)
{
    const float* seq = (const float*)d_in[0];
    const float* WQ  = (const float*)d_in[1];
    const float* bQ  = (const float*)d_in[2];
    const float* WK  = (const float*)d_in[3];
    const float* bK  = (const float*)d_in[4];
    const float* WV  = (const float*)d_in[5];
    const float* bV  = (const float*)d_in[6];
    _Float16* qkv = (_Float16*)d_ws;      // 3 * 2097152 halfs = 12.6 MB
    float* out = (float*)d_out;

    dim3 g1(64, H_, 3);
    qkv_gemm<<<g1, 256, 0, stream>>>(seq, WQ, bQ, WK, bK, WV, bV, qkv);
    dim3 g2(H_, B_);
    local_attn<<<g2, 256, 0, stream>>>(qkv, out);
}